// Round 10
// baseline (317.084 us; speedup 1.0000x reference)
//
#include <hip/hip_runtime.h>
#include <hip/hip_bf16.h>

// Attention with relative position bias: B=1, L=4096, D=512, H=8, HD=64
// bias[h,i,j] = rel[h, j-i+4095]

typedef __attribute__((ext_vector_type(8))) short bf16x8;
typedef __attribute__((ext_vector_type(4))) short bf16x4;
typedef __attribute__((ext_vector_type(4))) float f32x4;
typedef __attribute__((ext_vector_type(2))) unsigned u32x2;

#define QSCALE (0.125f * 1.4426950408889634f)   // 1/sqrt(64) * log2(e)

__device__ __forceinline__ short f2bf(float f) {
    unsigned u = __builtin_bit_cast(unsigned, f);
    u += 0x7fff + ((u >> 16) & 1);
    return (short)(u >> 16);
}

__device__ __forceinline__ f32x4 mfma32(bf16x8 a, bf16x8 b, f32x4 c) {
    return __builtin_amdgcn_mfma_f32_16x16x32_bf16(a, b, c, 0, 0, 0);
}

// 16x16x16 bf16 MFMA: B-operand k-layout (k = lg*4+e) matches swapped-QK^T
// S^T output rows (kv = lg*4+r) exactly -> P feeds PV without leaving registers.
__device__ __forceinline__ f32x4 mfma16(bf16x4 a, bf16x4 b, f32x4 c) {
#if __has_builtin(__builtin_amdgcn_mfma_f32_16x16x16bf16_1k)
    return __builtin_amdgcn_mfma_f32_16x16x16bf16_1k(a, b, c, 0, 0, 0);
#else
    // zero-pad K to 32 (correct, slower; no inline asm -> no hazard risk)
    const bf16x4 z4 = {0, 0, 0, 0};
    bf16x8 az = __builtin_shufflevector(a, z4, 0, 1, 2, 3, 4, 5, 6, 7);
    bf16x8 bz = __builtin_shufflevector(b, z4, 0, 1, 2, 3, 4, 5, 6, 7);
    return __builtin_amdgcn_mfma_f32_16x16x32_bf16(az, bz, c, 0, 0, 0);
#endif
}

// pack two f32 (>=0) to bf16 pair with half-up rounding, compiler-visible ops
__device__ __forceinline__ unsigned pack2bf(float lo, float hi) {
    unsigned ul = __builtin_bit_cast(unsigned, lo) + 0x8000u;
    unsigned uh = __builtin_bit_cast(unsigned, hi) + 0x8000u;
    // D = hi16(uh) << 16 | hi16(ul)
    return __builtin_amdgcn_perm(uh, ul, 0x07060302u);
}

// ---------------- prep kernels ----------------
__global__ __launch_bounds__(256) void k_prep_xp(const float* __restrict__ x,
                                                 const float* __restrict__ pos,
                                                 short* __restrict__ xp) {
    int i = (blockIdx.x * 256 + threadIdx.x) * 8;
    float4 a0 = *(const float4*)(x + i);
    float4 a1 = *(const float4*)(x + i + 4);
    float4 b0 = *(const float4*)(pos + i);
    float4 b1 = *(const float4*)(pos + i + 4);
    bf16x8 v;
    v[0] = f2bf(a0.x + b0.x); v[1] = f2bf(a0.y + b0.y);
    v[2] = f2bf(a0.z + b0.z); v[3] = f2bf(a0.w + b0.w);
    v[4] = f2bf(a1.x + b1.x); v[5] = f2bf(a1.y + b1.y);
    v[6] = f2bf(a1.z + b1.z); v[7] = f2bf(a1.w + b1.w);
    *(bf16x8*)(xp + i) = v;
}

__global__ __launch_bounds__(256) void k_prep_wqkv(const float* __restrict__ Wq,
                                                   const float* __restrict__ Wk,
                                                   const float* __restrict__ Wv,
                                                   short* __restrict__ WT) {
    int idx = blockIdx.x * 256 + threadIdx.x;   // 1536*512
    int n = idx >> 9, k = idx & 511;
    int nn = n & 511;
    const float* src = (n < 512) ? Wq : (n < 1024 ? Wk : Wv);
    float scale = (n < 512) ? QSCALE : 1.0f;
    WT[idx] = f2bf(src[k * 512 + nn] * scale);
}

__global__ __launch_bounds__(256) void k_prep_wo(const float* __restrict__ Wo,
                                                 short* __restrict__ WoT) {
    int idx = blockIdx.x * 256 + threadIdx.x;   // 512*512
    int n = idx >> 9, k = idx & 511;
    WoT[idx] = f2bf(Wo[k * 512 + n]);
}

// rel2 = rel * log2(e)   (f32, [8][8192])
__global__ __launch_bounds__(256) void k_prep_rel2(const float* __restrict__ rel,
                                                   float* __restrict__ rel2) {
    int i = blockIdx.x * 256 + threadIdx.x;
    rel2[i] = rel[i] * 1.4426950408889634f;
}

// V transpose: Vg [h][kv=4096][d=64] -> VT [h][d=64][kv=4096]
__global__ __launch_bounds__(256) void k_vt(const short* __restrict__ Vg,
                                            short* __restrict__ VT) {
    __shared__ short tile[64][72];
    const int tid = threadIdx.x;
    const int h = blockIdx.y, kvb = blockIdx.x * 64;
    const short* src = Vg + (size_t)h * 4096 * 64;
    short* dst = VT + (size_t)h * 64 * 4096;
    #pragma unroll
    for (int i = 0; i < 2; ++i) {
        int ch = tid + 256 * i;
        int r = ch >> 3, c = (ch & 7) * 8;
        *(uint4*)&tile[r][c] = *(const uint4*)(src + (size_t)(kvb + r) * 64 + c);
    }
    __syncthreads();
    #pragma unroll
    for (int i = 0; i < 2; ++i) {
        int ch = tid + 256 * i;
        int d = ch >> 3, kc = (ch & 7) * 8;
        bf16x8 v;
        #pragma unroll
        for (int j = 0; j < 8; ++j) v[j] = tile[kc + j][d];
        *(bf16x8*)(dst + (size_t)d * 4096 + kvb + kc) = v;
    }
}

// ---------------- GEMM: C[M x N] = A[M x 512] * Bt[N x 512]^T ----------------
template <int MODE>
__global__ __launch_bounds__(256) void k_gemm(const short* __restrict__ A,
                                              const short* __restrict__ Bt,
                                              const float* __restrict__ bias0,
                                              const float* __restrict__ bias1,
                                              const float* __restrict__ bias2,
                                              short* __restrict__ Qg,
                                              short* __restrict__ Kg,
                                              short* __restrict__ Vg,
                                              float* __restrict__ Cout) {
    __shared__ short Al[128][72];
    __shared__ short Bl[128][72];
    const int tid = threadIdx.x;
    const int lane = tid & 63, wid = tid >> 6;
    const int wm = wid >> 1, wn = wid & 1;
    const int mb = blockIdx.y * 128, nb = blockIdx.x * 128;
    const int lr = lane & 15, lg = lane >> 4;

    f32x4 acc[4][4] = {};

    for (int kk = 0; kk < 512; kk += 64) {
        #pragma unroll
        for (int i = 0; i < 4; ++i) {
            int o = tid + 256 * i;
            int row = o >> 3, c8 = (o & 7) * 8;
            *(uint4*)(&Al[row][c8]) = *(const uint4*)(A + (size_t)(mb + row) * 512 + kk + c8);
            *(uint4*)(&Bl[row][c8]) = *(const uint4*)(Bt + (size_t)(nb + row) * 512 + kk + c8);
        }
        __syncthreads();
        #pragma unroll
        for (int ks = 0; ks < 2; ++ks) {
            bf16x8 af[4], bfr[4];
            #pragma unroll
            for (int t = 0; t < 4; ++t) {
                af[t]  = *(const bf16x8*)(&Al[wm * 64 + t * 16 + lr][ks * 32 + lg * 8]);
                bfr[t] = *(const bf16x8*)(&Bl[wn * 64 + t * 16 + lr][ks * 32 + lg * 8]);
            }
            #pragma unroll
            for (int mt = 0; mt < 4; ++mt)
                #pragma unroll
                for (int nt = 0; nt < 4; ++nt)
                    acc[mt][nt] = mfma32(af[mt], bfr[nt], acc[mt][nt]);
        }
        __syncthreads();
    }

    #pragma unroll
    for (int mt = 0; mt < 4; ++mt) {
        #pragma unroll
        for (int nt = 0; nt < 4; ++nt) {
            #pragma unroll
            for (int r = 0; r < 4; ++r) {
                int m = mb + wm * 64 + mt * 16 + lg * 4 + r;
                int n = nb + wn * 64 + nt * 16 + lr;
                float v = acc[mt][nt][r];
                if (MODE == 0) {
                    int which = n >> 9;
                    int nn = n & 511;
                    int hh = nn >> 6, hd = nn & 63;
                    const float* bp = (which == 0) ? bias0 : (which == 1 ? bias1 : bias2);
                    v += bp[nn] * (which == 0 ? QSCALE : 1.0f);
                    short* dst = (which == 0) ? Qg : (which == 1 ? Kg : Vg);
                    dst[((size_t)hh * 4096 + m) * 64 + hd] = f2bf(v);
                } else {
                    Cout[(size_t)m * 512 + n] = v + bias0[n];
                }
            }
        }
    }
}

// ---------------- flash attention v6: all-register, zero LDS, zero fences ----
// grid 512: h = bid&7 (XCD-pinned), qb = (bid>>3)*64. 4 waves = 4 kv-quarters.
// Wave: 64 q rows (qt 0..3), 16 iters of kv64, t-outer (K/V frags live one t).
// PV via 16x16x16 MFMA: S^T lane layout IS the B-operand layout -> P stays in
// registers. No inline asm, no LDS, no barriers -- compiler schedules freely.
// Partial O/l -> Opar/Lpar; k_merge normalizes.
__global__ __launch_bounds__(256, 3) void k_attn5(const short* __restrict__ Qg,
                                                  const short* __restrict__ Kg,
                                                  const short* __restrict__ VT,
                                                  const float* __restrict__ rel2,
                                                  float* __restrict__ Opar,
                                                  float* __restrict__ Lpar) {
    const int tid = threadIdx.x;
    const int lane = tid & 63, s = tid >> 6;
    const int lr = lane & 15, lg = lane >> 4;
    const int bid = blockIdx.x;
    const int h = bid & 7;
    const int qb = (bid >> 3) * 64;

    const short* Qh = Qg + (size_t)h * 4096 * 64;
    const short* Kh = Kg + (size_t)h * 4096 * 64;
    const short* VTh = VT + (size_t)h * 64 * 4096;

    // Q fragments (B-operand): q = lr, d = dk*32 + lg*8 + e
    bf16x8 qf[4][2];
    #pragma unroll
    for (int qt = 0; qt < 4; ++qt)
        #pragma unroll
        for (int dk = 0; dk < 2; ++dk)
            qf[qt][dk] = *(const bf16x8*)(Qh + (size_t)(qb + qt * 16 + lr) * 64 + dk * 32 + lg * 8);

    const int kvbase = s * 1024;
    const short* kp = Kh + (size_t)kvbase * 64;                       // +4096/iter
    const short* vp = VTh + kvbase;                                   // +64/iter
    const float* bp = rel2 + h * 8192 + (kvbase + 4095 - qb) + lg * 4 - lr;  // +64/iter

    f32x4 acc[4][4] = {};   // [qt][dt]; lane: q = lr, d = dt*16 + lg*4 + r
    f32x4 lacc[4] = {};     // ones-row colsums (all 4 regs identical)

    const bf16x4 ones4 = {(short)0x3F80, (short)0x3F80, (short)0x3F80, (short)0x3F80};

    #pragma unroll 1
    for (int it = 0; it < 16; ++it) {
        #pragma unroll
        for (int t = 0; t < 4; ++t) {
            // K frags (A-operand of 16x16x32): kv = t*16+lr, d = dk*32+lg*8+e
            bf16x8 kf0 = *(const bf16x8*)(kp + (size_t)(t * 16 + lr) * 64 + lg * 8);
            bf16x8 kf1 = *(const bf16x8*)(kp + (size_t)(t * 16 + lr) * 64 + 32 + lg * 8);
            // V^T frags (A-operand of 16x16x16): d = dt*16+lr, kv = t*16+lg*4+e
            bf16x4 vf[4];
            #pragma unroll
            for (int dt = 0; dt < 4; ++dt)
                vf[dt] = *(const bf16x4*)(vp + (size_t)(dt * 16 + lr) * 4096 + t * 16 + lg * 4);

            #pragma unroll
            for (int qt = 0; qt < 4; ++qt) {
                // bias C-init: cin[r] = rel2[kv - q + 4095] (pre-scaled by log2e)
                const float* bq_ = bp + (t - qt) * 16;
                f32x4 cin = {bq_[0], bq_[1], bq_[2], bq_[3]};

                // S^T*log2e + bias ; p = exp2(.)  [lane: q=lr, kv=t*16+lg*4+r]
                f32x4 z = mfma32(kf0, qf[qt][0], cin);
                z = mfma32(kf1, qf[qt][1], z);

                u32x2 pk;
                pk[0] = pack2bf(exp2f(z[0]), exp2f(z[1]));
                pk[1] = pack2bf(exp2f(z[2]), exp2f(z[3]));
                bf16x4 pf = __builtin_bit_cast(bf16x4, pk);   // P[kv=t*16+lg*4+e][q=lr]

                // lsum via ones-row MFMA (colsum of P)
                lacc[qt] = mfma16(ones4, pf, lacc[qt]);
                // O^T += V^T_t · P_t   (16x16x16, P never leaves registers)
                #pragma unroll
                for (int dt = 0; dt < 4; ++dt)
                    acc[qt][dt] = mfma16(vf[dt], pf, acc[qt][dt]);
            }
        }
        kp += 64 * 64;
        vp += 64;
        bp += 64;
    }

    // ---- write unnormalized partials ----
    const size_t base = (size_t)(s * 8 + h) * 4096 + qb;
    #pragma unroll
    for (int qt = 0; qt < 4; ++qt) {
        #pragma unroll
        for (int dt = 0; dt < 4; ++dt)
            *(f32x4*)(Opar + (base + qt * 16 + lr) * 64 + dt * 16 + lg * 4) = acc[qt][dt];
        if (lg == 0) Lpar[base + qt * 16 + lr] = lacc[qt][0];
    }
}

// ---------------- merge: combine 4 kv-split partials, normalize, -> bf16 -----
__global__ __launch_bounds__(256) void k_merge(const float* __restrict__ Opar,
                                               const float* __restrict__ Lpar,
                                               short* __restrict__ AO) {
    int idx = blockIdx.x * 256 + threadIdx.x;   // 8*4096*16
    int dq = idx & 15;
    int q = (idx >> 4) & 4095;
    int h = idx >> 16;
    f32x4 sacc = {};
    float lt = 0.f;
    #pragma unroll
    for (int s = 0; s < 4; ++s) {
        sacc += *(const f32x4*)(Opar + ((size_t)(s * 8 + h) * 4096 + q) * 64 + dq * 4);
        lt += Lpar[(size_t)(s * 8 + h) * 4096 + q];
    }
    float inv = 1.0f / lt;
    bf16x4 o;
    o[0] = f2bf(sacc[0] * inv); o[1] = f2bf(sacc[1] * inv);
    o[2] = f2bf(sacc[2] * inv); o[3] = f2bf(sacc[3] * inv);
    *(bf16x4*)(AO + (size_t)q * 512 + h * 64 + dq * 4) = o;
}

// ---------------- launch ----------------
extern "C" void kernel_launch(void* const* d_in, const int* in_sizes, int n_in,
                              void* d_out, int out_size, void* d_ws, size_t ws_size,
                              hipStream_t stream) {
    const float* x   = (const float*)d_in[0];
    const float* pos = (const float*)d_in[1];
    const float* rel = (const float*)d_in[2];
    const float* Wq  = (const float*)d_in[3];
    const float* bq  = (const float*)d_in[4];
    const float* Wk  = (const float*)d_in[5];
    const float* bk  = (const float*)d_in[6];
    const float* Wv  = (const float*)d_in[7];
    const float* bv  = (const float*)d_in[8];
    const float* Wo  = (const float*)d_in[9];
    const float* bo  = (const float*)d_in[10];
    float* out = (float*)d_out;

    char* ws = (char*)d_ws;
    short* xp    = (short*)ws;  ws += (size_t)4096 * 512 * 2;   // reused as VT after gemm0
    short* WqkvT = (short*)ws;  ws += (size_t)1536 * 512 * 2;
    short* WoT   = (short*)ws;  ws += (size_t)512 * 512 * 2;
    short* Qg    = (short*)ws;  ws += (size_t)8 * 4096 * 64 * 2;
    short* Kg    = (short*)ws;  ws += (size_t)8 * 4096 * 64 * 2;
    short* Vg    = (short*)ws;  ws += (size_t)8 * 4096 * 64 * 2;
    short* AO    = (short*)ws;  ws += (size_t)4096 * 512 * 2;
    float* rel2  = (float*)ws;  ws += (size_t)8 * 8192 * 4;
    float* Opar  = (float*)ws;  ws += (size_t)4 * 8 * 4096 * 64 * 4;
    float* Lpar  = (float*)ws;  ws += (size_t)4 * 8 * 4096 * 4;
    short* VT    = xp;          // xp is dead after k_gemm<0>

    k_prep_xp<<<dim3(4096 * 512 / (256 * 8)), 256, 0, stream>>>(x, pos, xp);
    k_prep_wqkv<<<dim3(1536 * 512 / 256), 256, 0, stream>>>(Wq, Wk, Wv, WqkvT);
    k_prep_wo<<<dim3(512 * 512 / 256), 256, 0, stream>>>(Wo, WoT);
    k_prep_rel2<<<dim3(8 * 8192 / 256), 256, 0, stream>>>(rel, rel2);

    k_gemm<0><<<dim3(12, 32), 256, 0, stream>>>(xp, WqkvT, bq, bk, bv, Qg, Kg, Vg, nullptr);
    k_vt<<<dim3(64, 8), 256, 0, stream>>>(Vg, VT);
    k_attn5<<<dim3(512), 256, 0, stream>>>(Qg, Kg, VT, rel2, Opar, Lpar);
    k_merge<<<dim3(2048), 256, 0, stream>>>(Opar, Lpar, AO);
    k_gemm<1><<<dim3(4, 32), 256, 0, stream>>>(AO, WoT, bo, nullptr, nullptr,
                                               nullptr, nullptr, nullptr, out);
}

// Round 11
// 139.106 us; speedup vs baseline: 2.2794x; 2.2794x over previous
//
#include <hip/hip_runtime.h>
#include <hip/hip_bf16.h>

// Attention with relative position bias: B=1, L=4096, D=512, H=8, HD=64
// bias[h,i,j] = rel[h, j-i+4095]

typedef __attribute__((ext_vector_type(8))) short bf16x8;
typedef __attribute__((ext_vector_type(4))) short bf16x4;
typedef __attribute__((ext_vector_type(4))) float f32x4;
typedef __attribute__((ext_vector_type(2))) unsigned u32x2;

#define QSCALE (0.125f * 1.4426950408889634f)   // 1/sqrt(64) * log2(e)

__device__ __forceinline__ short f2bf(float f) {
    unsigned u = __builtin_bit_cast(unsigned, f);
    u += 0x7fff + ((u >> 16) & 1);
    return (short)(u >> 16);
}

__device__ __forceinline__ f32x4 mfma32(bf16x8 a, bf16x8 b, f32x4 c) {
    return __builtin_amdgcn_mfma_f32_16x16x32_bf16(a, b, c, 0, 0, 0);
}

__device__ __forceinline__ unsigned cvtpk(float a, float b) {
    unsigned r;
    asm("v_cvt_pk_bf16_f32 %0, %1, %2" : "=v"(r) : "v"(a), "v"(b));
    return r;
}

// ---------------- prep kernels ----------------
__global__ __launch_bounds__(256) void k_prep_xp(const float* __restrict__ x,
                                                 const float* __restrict__ pos,
                                                 short* __restrict__ xp) {
    int i = (blockIdx.x * 256 + threadIdx.x) * 8;
    float4 a0 = *(const float4*)(x + i);
    float4 a1 = *(const float4*)(x + i + 4);
    float4 b0 = *(const float4*)(pos + i);
    float4 b1 = *(const float4*)(pos + i + 4);
    bf16x8 v;
    v[0] = f2bf(a0.x + b0.x); v[1] = f2bf(a0.y + b0.y);
    v[2] = f2bf(a0.z + b0.z); v[3] = f2bf(a0.w + b0.w);
    v[4] = f2bf(a1.x + b1.x); v[5] = f2bf(a1.y + b1.y);
    v[6] = f2bf(a1.z + b1.z); v[7] = f2bf(a1.w + b1.w);
    *(bf16x8*)(xp + i) = v;
}

__global__ __launch_bounds__(256) void k_prep_wqkv(const float* __restrict__ Wq,
                                                   const float* __restrict__ Wk,
                                                   const float* __restrict__ Wv,
                                                   short* __restrict__ WT) {
    int idx = blockIdx.x * 256 + threadIdx.x;   // 1536*512
    int n = idx >> 9, k = idx & 511;
    int nn = n & 511;
    const float* src = (n < 512) ? Wq : (n < 1024 ? Wk : Wv);
    float scale = (n < 512) ? QSCALE : 1.0f;
    WT[idx] = f2bf(src[k * 512 + nn] * scale);
}

__global__ __launch_bounds__(256) void k_prep_wo(const float* __restrict__ Wo,
                                                 short* __restrict__ WoT) {
    int idx = blockIdx.x * 256 + threadIdx.x;   // 512*512
    int n = idx >> 9, k = idx & 511;
    WoT[idx] = f2bf(Wo[k * 512 + n]);
}

// rel2 = rel * log2(e)   (f32, [8][8192])
__global__ __launch_bounds__(256) void k_prep_rel2(const float* __restrict__ rel,
                                                   float* __restrict__ rel2) {
    int i = blockIdx.x * 256 + threadIdx.x;
    rel2[i] = rel[i] * 1.4426950408889634f;
}

// V transpose: Vg [h][kv=4096][d=64] -> VT [h][d=64][kv=4096]
__global__ __launch_bounds__(256) void k_vt(const short* __restrict__ Vg,
                                            short* __restrict__ VT) {
    __shared__ short tile[64][72];
    const int tid = threadIdx.x;
    const int h = blockIdx.y, kvb = blockIdx.x * 64;
    const short* src = Vg + (size_t)h * 4096 * 64;
    short* dst = VT + (size_t)h * 64 * 4096;
    #pragma unroll
    for (int i = 0; i < 2; ++i) {
        int ch = tid + 256 * i;
        int r = ch >> 3, c = (ch & 7) * 8;
        *(uint4*)&tile[r][c] = *(const uint4*)(src + (size_t)(kvb + r) * 64 + c);
    }
    __syncthreads();
    #pragma unroll
    for (int i = 0; i < 2; ++i) {
        int ch = tid + 256 * i;
        int d = ch >> 3, kc = (ch & 7) * 8;
        bf16x8 v;
        #pragma unroll
        for (int j = 0; j < 8; ++j) v[j] = tile[kc + j][d];
        *(bf16x8*)(dst + (size_t)d * 4096 + kvb + kc) = v;
    }
}

// ---------------- GEMM: C[M x N] = A[M x 512] * Bt[N x 512]^T ----------------
template <int MODE>
__global__ __launch_bounds__(256) void k_gemm(const short* __restrict__ A,
                                              const short* __restrict__ Bt,
                                              const float* __restrict__ bias0,
                                              const float* __restrict__ bias1,
                                              const float* __restrict__ bias2,
                                              short* __restrict__ Qg,
                                              short* __restrict__ Kg,
                                              short* __restrict__ Vg,
                                              float* __restrict__ Cout) {
    __shared__ short Al[128][72];
    __shared__ short Bl[128][72];
    const int tid = threadIdx.x;
    const int lane = tid & 63, wid = tid >> 6;
    const int wm = wid >> 1, wn = wid & 1;
    const int mb = blockIdx.y * 128, nb = blockIdx.x * 128;
    const int lr = lane & 15, lg = lane >> 4;

    f32x4 acc[4][4] = {};

    for (int kk = 0; kk < 512; kk += 64) {
        #pragma unroll
        for (int i = 0; i < 4; ++i) {
            int o = tid + 256 * i;
            int row = o >> 3, c8 = (o & 7) * 8;
            *(uint4*)(&Al[row][c8]) = *(const uint4*)(A + (size_t)(mb + row) * 512 + kk + c8);
            *(uint4*)(&Bl[row][c8]) = *(const uint4*)(Bt + (size_t)(nb + row) * 512 + kk + c8);
        }
        __syncthreads();
        #pragma unroll
        for (int ks = 0; ks < 2; ++ks) {
            bf16x8 af[4], bfr[4];
            #pragma unroll
            for (int t = 0; t < 4; ++t) {
                af[t]  = *(const bf16x8*)(&Al[wm * 64 + t * 16 + lr][ks * 32 + lg * 8]);
                bfr[t] = *(const bf16x8*)(&Bl[wn * 64 + t * 16 + lr][ks * 32 + lg * 8]);
            }
            #pragma unroll
            for (int mt = 0; mt < 4; ++mt)
                #pragma unroll
                for (int nt = 0; nt < 4; ++nt)
                    acc[mt][nt] = mfma32(af[mt], bfr[nt], acc[mt][nt]);
        }
        __syncthreads();
    }

    #pragma unroll
    for (int mt = 0; mt < 4; ++mt) {
        #pragma unroll
        for (int nt = 0; nt < 4; ++nt) {
            #pragma unroll
            for (int r = 0; r < 4; ++r) {
                int m = mb + wm * 64 + mt * 16 + lg * 4 + r;
                int n = nb + wn * 64 + nt * 16 + lr;
                float v = acc[mt][nt][r];
                if (MODE == 0) {
                    int which = n >> 9;
                    int nn = n & 511;
                    int hh = nn >> 6, hd = nn & 63;
                    const float* bp = (which == 0) ? bias0 : (which == 1 ? bias1 : bias2);
                    v += bp[nn] * (which == 0 ? QSCALE : 1.0f);
                    short* dst = (which == 0) ? Qg : (which == 1 ? Kg : Vg);
                    dst[((size_t)hh * 4096 + m) * 64 + hd] = f2bf(v);
                } else {
                    Cout[(size_t)m * 512 + n] = v + bias0[n];
                }
            }
        }
    }
}

// ---------------- flash attention v7: r7 loop + partials epilogue ------------
// EXACTLY the r7-proven k_attn3 loop (86.7us, no spill, VGPR 120). Only change:
// the 70KB in-LDS merge epilogue (which capped occupancy at 2 blocks/CU) is
// replaced by direct partial O/l writes + k_merge (r9-proven pattern).
// LDS 70656 -> 9216 B  =>  occupancy becomes VGPR-limited (~4 blocks/CU).
// grid 512: h = bid&7 (XCD-pinned), qb = (bid>>3)*64. 4 waves = 4 kv quarters.
__global__ __launch_bounds__(256, 2) void k_attn6(const short* __restrict__ Qg,
                                                  const short* __restrict__ Kg,
                                                  const short* __restrict__ VT,
                                                  const float* __restrict__ rel2,
                                                  float* __restrict__ Opar,
                                                  float* __restrict__ Lpar) {
    __shared__ __align__(16) char smem[9216];   // 4 waves x [16 q][72 kv] shorts

    const int tid = threadIdx.x;
    const int lane = tid & 63, sp = tid >> 6;
    const int lr = lane & 15, lg = lane >> 4;
    const int bid = blockIdx.x;
    const int h = bid & 7;
    const int qb = (bid >> 3) * 64;

    short* Pw = (short*)smem + sp * 1152;

    const short* Qh = Qg + (size_t)h * 4096 * 64;
    const short* Kh = Kg + (size_t)h * 4096 * 64;
    const short* VTh = VT + (size_t)h * 64 * 4096;

    // Q fragments (B-operand): q = lr, d = dk*32 + lg*8 + e
    bf16x8 qf[4][2];
    #pragma unroll
    for (int qt = 0; qt < 4; ++qt)
        #pragma unroll
        for (int dk = 0; dk < 2; ++dk)
            qf[qt][dk] = *(const bf16x8*)(Qh + (size_t)(qb + qt * 16 + lr) * 64 + dk * 32 + lg * 8);

    const int kvbase = sp * 1024;
    const short* kp = Kh + (size_t)kvbase * 64;                       // +4096/iter
    const short* vp = VTh + kvbase;                                   // +64/iter
    const float* bp = rel2 + h * 8192 + (kvbase + 4095 - qb) + lg * 4 - lr;  // +64/iter

    f32x4 acc[4][4] = {};   // [qt][dt]; lane: q = lr, d = dt*16 + lg*4 + r
    f32x4 lacc[4] = {};     // ones-row colsums (all 4 regs identical)

    bf16x8 ones;
    #pragma unroll
    for (int i = 0; i < 8; ++i) ones[i] = (short)0x3F80;   // bf16 1.0

    #pragma unroll 1
    for (int it = 0; it < 16; ++it) {
        // K frags (A-operand): kv = t*16+lr, d = dk*32+lg*8+e  [global, L2]
        bf16x8 kf[4][2];
        #pragma unroll
        for (int t = 0; t < 4; ++t) {
            kf[t][0] = *(const bf16x8*)(kp + (size_t)(t * 16 + lr) * 64 + lg * 8);
            kf[t][1] = *(const bf16x8*)(kp + (size_t)(t * 16 + lr) * 64 + 32 + lg * 8);
        }
        // V^T frags (A-operand): d = dt*16+lr, kv = w*32+lg*8+e  [global, L2]
        bf16x8 vf[4][2];
        #pragma unroll
        for (int dt = 0; dt < 4; ++dt)
            #pragma unroll
            for (int w = 0; w < 2; ++w)
                vf[dt][w] = *(const bf16x8*)(vp + (size_t)(dt * 16 + lr) * 4096 + w * 32 + lg * 8);

        #pragma unroll
        for (int qt = 0; qt < 4; ++qt) {
            // bias C-init: cin[t][r] = rel2[kv - q + 4095] (already *log2e)
            f32x4 cin[4];
            #pragma unroll
            for (int t = 0; t < 4; ++t)
                #pragma unroll
                for (int r = 0; r < 4; ++r)
                    cin[t][r] = bp[(t - qt) * 16 + r];

            // S^T*log2e + bias = K·Q' + C ; p = exp2(.)
            unsigned pk0[4], pk1[4];
            #pragma unroll
            for (int t = 0; t < 4; ++t) {
                f32x4 z = mfma32(kf[t][0], qf[qt][0], cin[t]);
                z = mfma32(kf[t][1], qf[qt][1], z);
                float p0 = exp2f(z[0]), p1 = exp2f(z[1]);
                float p2 = exp2f(z[2]), p3 = exp2f(z[3]);
                pk0[t] = cvtpk(p0, p1);
                pk1[t] = cvtpk(p2, p3);
            }

            // WAR fence: previous qt's P reads must finish before overwrite
            asm volatile("s_waitcnt lgkmcnt(0)" ::: "memory");
            __builtin_amdgcn_sched_barrier(0);
            #pragma unroll
            for (int t = 0; t < 4; ++t) {
                u32x2 pk;
                pk[0] = pk0[t]; pk[1] = pk1[t];
                *(u32x2*)(Pw + lr * 72 + t * 16 + lg * 4) = pk;   // P[q=lr][kv]
            }
            __builtin_amdgcn_sched_barrier(0);

            // B-frags: P[kv = w*32+lg*8+e][q = lr]
            bf16x8 pb0 = *(const bf16x8*)(Pw + lr * 72 + lg * 8);
            bf16x8 pb1 = *(const bf16x8*)(Pw + lr * 72 + 32 + lg * 8);

            // lsum via ones-row MFMA (colsum of P)
            lacc[qt] = mfma32(ones, pb0, lacc[qt]);
            lacc[qt] = mfma32(ones, pb1, lacc[qt]);

            // O^T += V^T · P
            #pragma unroll
            for (int dt = 0; dt < 4; ++dt) {
                acc[qt][dt] = mfma32(vf[dt][0], pb0, acc[qt][dt]);
                acc[qt][dt] = mfma32(vf[dt][1], pb1, acc[qt][dt]);
            }
        }
        kp += 64 * 64;
        vp += 64;
        bp += 64;
    }

    // ---- write unnormalized partials (r9-proven pattern; no LDS overlay) ----
    const size_t base = (size_t)(sp * 8 + h) * 4096 + qb;
    #pragma unroll
    for (int qt = 0; qt < 4; ++qt) {
        #pragma unroll
        for (int dt = 0; dt < 4; ++dt)
            *(f32x4*)(Opar + (base + qt * 16 + lr) * 64 + dt * 16 + lg * 4) = acc[qt][dt];
        if (lg == 0) Lpar[base + qt * 16 + lr] = lacc[qt][0];
    }
}

// ---------------- merge: combine 4 kv-split partials, normalize, -> bf16 -----
__global__ __launch_bounds__(256) void k_merge(const float* __restrict__ Opar,
                                               const float* __restrict__ Lpar,
                                               short* __restrict__ AO) {
    int idx = blockIdx.x * 256 + threadIdx.x;   // 8*4096*16
    int dq = idx & 15;
    int q = (idx >> 4) & 4095;
    int h = idx >> 16;
    f32x4 sacc = {};
    float lt = 0.f;
    #pragma unroll
    for (int s = 0; s < 4; ++s) {
        sacc += *(const f32x4*)(Opar + ((size_t)(s * 8 + h) * 4096 + q) * 64 + dq * 4);
        lt += Lpar[(size_t)(s * 8 + h) * 4096 + q];
    }
    float inv = 1.0f / lt;
    bf16x4 o;
    o[0] = f2bf(sacc[0] * inv); o[1] = f2bf(sacc[1] * inv);
    o[2] = f2bf(sacc[2] * inv); o[3] = f2bf(sacc[3] * inv);
    *(bf16x4*)(AO + (size_t)q * 512 + h * 64 + dq * 4) = o;
}

// ---------------- launch ----------------
extern "C" void kernel_launch(void* const* d_in, const int* in_sizes, int n_in,
                              void* d_out, int out_size, void* d_ws, size_t ws_size,
                              hipStream_t stream) {
    const float* x   = (const float*)d_in[0];
    const float* pos = (const float*)d_in[1];
    const float* rel = (const float*)d_in[2];
    const float* Wq  = (const float*)d_in[3];
    const float* bq  = (const float*)d_in[4];
    const float* Wk  = (const float*)d_in[5];
    const float* bk  = (const float*)d_in[6];
    const float* Wv  = (const float*)d_in[7];
    const float* bv  = (const float*)d_in[8];
    const float* Wo  = (const float*)d_in[9];
    const float* bo  = (const float*)d_in[10];
    float* out = (float*)d_out;

    char* ws = (char*)d_ws;
    short* xp    = (short*)ws;  ws += (size_t)4096 * 512 * 2;   // reused as VT after gemm0
    short* WqkvT = (short*)ws;  ws += (size_t)1536 * 512 * 2;
    short* WoT   = (short*)ws;  ws += (size_t)512 * 512 * 2;
    short* Qg    = (short*)ws;  ws += (size_t)8 * 4096 * 64 * 2;
    short* Kg    = (short*)ws;  ws += (size_t)8 * 4096 * 64 * 2;
    short* Vg    = (short*)ws;  ws += (size_t)8 * 4096 * 64 * 2;
    short* AO    = (short*)ws;  ws += (size_t)4096 * 512 * 2;
    float* rel2  = (float*)ws;  ws += (size_t)8 * 8192 * 4;
    float* Opar  = (float*)ws;  ws += (size_t)4 * 8 * 4096 * 64 * 4;
    float* Lpar  = (float*)ws;  ws += (size_t)4 * 8 * 4096 * 4;
    short* VT    = xp;          // xp is dead after k_gemm<0>

    k_prep_xp<<<dim3(4096 * 512 / (256 * 8)), 256, 0, stream>>>(x, pos, xp);
    k_prep_wqkv<<<dim3(1536 * 512 / 256), 256, 0, stream>>>(Wq, Wk, Wv, WqkvT);
    k_prep_wo<<<dim3(512 * 512 / 256), 256, 0, stream>>>(Wo, WoT);
    k_prep_rel2<<<dim3(8 * 8192 / 256), 256, 0, stream>>>(rel, rel2);

    k_gemm<0><<<dim3(12, 32), 256, 0, stream>>>(xp, WqkvT, bq, bk, bv, Qg, Kg, Vg, nullptr);
    k_vt<<<dim3(64, 8), 256, 0, stream>>>(Vg, VT);
    k_attn6<<<dim3(512), 256, 0, stream>>>(Qg, Kg, VT, rel2, Opar, Lpar);
    k_merge<<<dim3(2048), 256, 0, stream>>>(Opar, Lpar, AO);
    k_gemm<1><<<dim3(4, 32), 256, 0, stream>>>(AO, WoT, bo, nullptr, nullptr,
                                               nullptr, nullptr, nullptr, out);
}